// Round 21
// baseline (497.444 us; speedup 1.0000x reference)
//
#include <hip/hip_runtime.h>

// ---- problem dims (fixed) ----
#define T_TOK 8192      // B*S
#define DMODEL 1024
#define NEXP 8
#define TOPK 2
#define HID 4096
#define NPAIR (T_TOK*TOPK)   // 16384
#define BM 128
#define BN 128
#define BK 64
#define MAXT (NPAIR/128 + NEXP)   // 136 row-tiles upper bound

typedef unsigned short u16;
typedef unsigned int u32;
typedef short s16x8 __attribute__((ext_vector_type(8)));
typedef float f32x4 __attribute__((ext_vector_type(4)));

// fp32 -> bf16 round-to-nearest-even
__device__ __forceinline__ u16 f2b(float f) {
    union { float f; unsigned int u; } v; v.f = f;
    return (u16)((v.u + 0x7fffu + ((v.u >> 16) & 1u)) >> 16);
}
__device__ __forceinline__ float b2f(u16 h) {
    union { unsigned int u; float f; } v; v.u = ((unsigned int)h) << 16;
    return v.f;
}

__device__ __forceinline__ s16x8 cvt8(float4 f0, float4 f1) {
    s16x8 o;
    o[0]=(short)f2b(f0.x); o[1]=(short)f2b(f0.y); o[2]=(short)f2b(f0.z); o[3]=(short)f2b(f0.w);
    o[4]=(short)f2b(f1.x); o[5]=(short)f2b(f1.y); o[6]=(short)f2b(f1.z); o[7]=(short)f2b(f1.w);
    return o;
}

// async global->LDS, 16B per lane; LDS dest linear in lane order
__device__ __forceinline__ void gload16(const void* g, void* l) {
    __builtin_amdgcn_global_load_lds(
        (const __attribute__((address_space(1))) unsigned int*)g,
        (__attribute__((address_space(3))) unsigned int*)l, 16, 0, 0);
}

// tanh-form gelu, exp/rcp in HW
__device__ __forceinline__ float gelu_fast(float v) {
    float y = 0.7978845608028654f * v * fmaf(0.044715f * v, v, 1.0f);
    float t = -2.8853900817779268f * y;   // -2y * log2(e)
    float z, r;
    asm("v_exp_f32 %0, %1" : "=v"(z) : "v"(t));
    float den = 1.0f + z;
    asm("v_rcp_f32 %0, %1" : "=v"(r) : "v"(den));
    return v * r;
}

// m204 bijective XCD swizzle over nact active blocks
__device__ __forceinline__ int xcd_swz(int bid, int nact) {
    int q = nact >> 3, r = nact & 7;
    int xcd = bid & 7, i = bid >> 3;
    return (xcd < r ? xcd * (q + 1) : r * (q + 1) + (xcd - r) * q) + i;
}

// ---------------- fp32 -> bf16 conversion (x only) ----------------
__global__ __launch_bounds__(256) void cvt_kernel(const float* __restrict__ in,
                                                  u16* __restrict__ out, long n8) {
    long stride = (long)gridDim.x * 256;
    for (long i = (long)blockIdx.x * 256 + threadIdx.x; i < n8; i += stride) {
        const float4* p = (const float4*)(in + i * 8);
        float4 f0 = p[0], f1 = p[1];
        *(s16x8*)(out + i * 8) = cvt8(f0, f1);
    }
}

// ---------------- router (NO atomics; topi/topw only + folded W1 convert) ----------------
__global__ __launch_bounds__(256) void router_kernel(
    const float* __restrict__ x, const float* __restrict__ Wr, const float* __restrict__ br,
    int* __restrict__ topi, float* __restrict__ topw,
    const float* __restrict__ W1, u16* __restrict__ W1b)
{
    __shared__ float WrS[NEXP * DMODEL];
    int tid = threadIdx.x;
    const float4* Wr4 = (const float4*)Wr;
    float4* WrS4 = (float4*)WrS;
    for (int i = tid; i < NEXP * DMODEL / 4; i += 256) WrS4[i] = Wr4[i];
    __syncthreads();

    int wid = tid >> 6, lane = tid & 63;
    int t = blockIdx.x * 4 + wid;
    const float* xr = x + (size_t)t * DMODEL;

    float acc[NEXP];
#pragma unroll
    for (int e = 0; e < NEXP; ++e) acc[e] = 0.f;
#pragma unroll 4
    for (int i = lane; i < DMODEL; i += 64) {
        float xv = xr[i];
#pragma unroll
        for (int e = 0; e < NEXP; ++e) acc[e] = fmaf(xv, WrS[e * DMODEL + i], acc[e]);
    }
#pragma unroll
    for (int e = 0; e < NEXP; ++e) {
        float v = acc[e];
#pragma unroll
        for (int off = 32; off > 0; off >>= 1) v += __shfl_xor(v, off);
        acc[e] = v;
    }
    if (lane == 0) {
        float lg[NEXP];
#pragma unroll
        for (int e = 0; e < NEXP; ++e) lg[e] = acc[e] + br[e];
        int i1 = 0;
#pragma unroll
        for (int e = 1; e < NEXP; ++e) if (lg[e] > lg[i1]) i1 = e;
        int i2 = (i1 == 0) ? 1 : 0;
#pragma unroll
        for (int e = 0; e < NEXP; ++e) if (e != i1 && lg[e] > lg[i2]) i2 = e;
        float e2 = expf(lg[i2] - lg[i1]);
        float s = 1.f + e2;
        topi[t * 2] = i1;  topi[t * 2 + 1] = i2;
        topw[t * 2] = 1.f / s;  topw[t * 2 + 1] = e2 / s;
    }

    // folded W1 convert (completes before gemm1 via kernel-boundary ordering)
    long n8 = (long)NEXP * DMODEL * HID / 8;
    long stride = (long)gridDim.x * 256;
    for (long i = (long)blockIdx.x * 256 + tid; i < n8; i += stride) {
        const float4* p = (const float4*)(W1 + i * 8);
        float4 f0 = p[0], f1 = p[1];
        *(s16x8*)(W1b + i * 8) = cvt8(f0, f1);
    }
}

// single-block count + offsets + tile table (no atomics anywhere)
__global__ __launch_bounds__(256) void count_offsets_kernel(
    const int* __restrict__ topi, int* __restrict__ cnt, int* __restrict__ offs,
    u32* __restrict__ table, int* __restrict__ meta)
{
    __shared__ int red[NEXP * 256];
    int tid = threadIdx.x;
    int c[NEXP] = {};
    for (int i = tid; i < NPAIR; i += 256) {
        int e = topi[i];
#pragma unroll
        for (int k = 0; k < NEXP; ++k) c[k] += (e == k) ? 1 : 0;   // static idx (rule #20)
    }
#pragma unroll
    for (int k = 0; k < NEXP; ++k) red[k * 256 + tid] = c[k];
    __syncthreads();
    if (tid < NEXP) {
        int s = 0;
        for (int i = 0; i < 256; ++i) s += red[tid * 256 + i];
        cnt[tid] = s;
    }
    __syncthreads();
    if (tid == 0) {
        int a = 0;
        for (int e = 0; e < NEXP; ++e) { offs[e] = a; a += cnt[e]; }
        offs[NEXP] = a;
        int nt = 0;
        for (int e = 0; e < NEXP; ++e)
            for (int r0 = 0; r0 < cnt[e]; r0 += 128)
                table[nt++] = ((u32)e << 20) | (u32)r0;
        meta[0] = nt;
    }
}

// wave-aggregated scatter; fill padded to 128B/expert (parallel L2 lines)
__global__ __launch_bounds__(256) void scatter_kernel(
    const int* __restrict__ topi, const float* __restrict__ topw,
    const int* __restrict__ offs, int* __restrict__ fill,
    int* __restrict__ tok, float* __restrict__ wgt, int* __restrict__ pos)
{
    int t = blockIdx.x * 256 + threadIdx.x;
    int lane = threadIdx.x & 63;
#pragma unroll
    for (int s = 0; s < TOPK; ++s) {
        int e = topi[t * 2 + s];
        float w = topw[t * 2 + s];
#pragma unroll
        for (int ex = 0; ex < NEXP; ++ex) {
            unsigned long long m = __ballot(e == ex);
            if (e == ex) {
                int ldr = (int)__ffsll((unsigned long long)m) - 1;
                int base = 0;
                if (lane == ldr) base = atomicAdd(&fill[ex * 32], (int)__popcll(m));
                base = __shfl(base, ldr);
                int mypos = base + (int)__popcll(m & ((1ull << lane) - 1ull));
                int p = offs[ex] + mypos;
                tok[p] = t;
                wgt[p] = w;
                pos[t * 2 + s] = p;
            }
        }
    }
}

// combine: out[t][d] = sum over 2 pair-slots x 2 K-half planes of Opair
__global__ __launch_bounds__(256) void combine_kernel(
    const u16* __restrict__ Op, const int* __restrict__ pos, float* __restrict__ out)
{
    const size_t PL = (size_t)NPAIR * DMODEL;   // plane stride
    int tid = threadIdx.x;
    int t = blockIdx.x * 2 + (tid >> 7);
    int c = (tid & 127) * 8;
    int pa = pos[t * 2], pb = pos[t * 2 + 1];
    s16x8 a0 = *(const s16x8*)(Op + (size_t)pa * DMODEL + c);
    s16x8 a1 = *(const s16x8*)(Op + PL + (size_t)pa * DMODEL + c);
    s16x8 b0 = *(const s16x8*)(Op + (size_t)pb * DMODEL + c);
    s16x8 b1 = *(const s16x8*)(Op + PL + (size_t)pb * DMODEL + c);
    float* o = out + (size_t)t * DMODEL + c;
    float4 o0, o1;
    o0.x = (b2f((u16)a0[0]) + b2f((u16)a1[0])) + (b2f((u16)b0[0]) + b2f((u16)b1[0]));
    o0.y = (b2f((u16)a0[1]) + b2f((u16)a1[1])) + (b2f((u16)b0[1]) + b2f((u16)b1[1]));
    o0.z = (b2f((u16)a0[2]) + b2f((u16)a1[2])) + (b2f((u16)b0[2]) + b2f((u16)b1[2]));
    o0.w = (b2f((u16)a0[3]) + b2f((u16)a1[3])) + (b2f((u16)b0[3]) + b2f((u16)b1[3]));
    o1.x = (b2f((u16)a0[4]) + b2f((u16)a1[4])) + (b2f((u16)b0[4]) + b2f((u16)b1[4]));
    o1.y = (b2f((u16)a0[5]) + b2f((u16)a1[5])) + (b2f((u16)b0[5]) + b2f((u16)b1[5]));
    o1.z = (b2f((u16)a0[6]) + b2f((u16)a1[6])) + (b2f((u16)b0[6]) + b2f((u16)b1[6]));
    o1.w = (b2f((u16)a0[7]) + b2f((u16)a1[7])) + (b2f((u16)b0[7]) + b2f((u16)b1[7]));
    ((float4*)o)[0] = o0;
    ((float4*)o)[1] = o1;
}

// ======== m97-replica GEMM core, 8-wave variant: 128x128, BK=64, 512 thr ====
// (2x4 wave grid; wave tile 64x32 -> acc[4][2]); SINGLE 32 KiB LDS buffer,
// 2 barriers per 64-K step. Same layout/swizzle as R2-R20 (slot = s^(row&7)).
#define STAGE_TILE(koff) do {                                               \
    _Pragma("unroll") for (int c = 0; c < 2; ++c) {                         \
        int idx = c * 512 + tid;                                            \
        gload16(Agp + aoffA[c] + (size_t)(koff), (char*)As + idx * 16);     \
        gload16(Bgp + boffB[c] + (size_t)(koff), (char*)Bs + idx * 16);     \
    }                                                                       \
} while (0)

#define COMPUTE_TILE() do {                                                 \
    _Pragma("unroll") for (int half = 0; half < 2; ++half) {                \
        s16x8 av[4], bv[2];                                                 \
        int kslot = half * 4 + (lane >> 4);                                 \
        _Pragma("unroll") for (int mi = 0; mi < 4; ++mi) {                  \
            int rr = wm * 64 + mi * 16 + (lane & 15);                       \
            av[mi] = *(const s16x8*)((char*)As + rr * 128 + ((kslot ^ (rr & 7)) * 16)); } \
        _Pragma("unroll") for (int nf = 0; nf < 2; ++nf) {                  \
            int rb = wn * 32 + nf * 16 + (lane & 15);                       \
            bv[nf] = *(const s16x8*)((char*)Bs + rb * 128 + ((kslot ^ (rb & 7)) * 16)); } \
        _Pragma("unroll") for (int mi = 0; mi < 4; ++mi)                    \
        _Pragma("unroll") for (int nf = 0; nf < 2; ++nf)                    \
            acc[mi][nf] = __builtin_amdgcn_mfma_f32_16x16x32_bf16(          \
                av[mi], bv[nf], acc[mi][nf], 0, 0, 0);                      \
    }                                                                       \
} while (0)

#define VM0() asm volatile("s_waitcnt vmcnt(0)" ::: "memory")

#define M97_LOOP(NT, KBASE) do {                                            \
    _Pragma("unroll 1")                                                     \
    for (int t = 0; t < (NT); ++t) {                                        \
        STAGE_TILE((size_t)(KBASE) + (size_t)t * BK);                       \
        VM0();                                                              \
        __syncthreads();                                                    \
        COMPUTE_TILE();                                                     \
        __syncthreads();                                                    \
    }                                                                       \
} while (0)

// staging chunk math: 1024 chunks/operand (128 rows x 8 slots), 2/thread
#define CHUNK_RS(c)                                                         \
    int r##c = ((c) * 512 + tid) >> 3;                                      \
    int s##c = (tid & 7) ^ (r##c & 7);

// GEMM1: H1[p, n] = gelu( sum_d xb[tok[p], d] * W1b[e, n, d] + b1[e, n] )
// + folded W2 fp32->bf16 convert on pass 0
__global__ __launch_bounds__(512, 4) void gemm1_kernel(
    const u16* __restrict__ xb, const u16* __restrict__ W1b, const float* __restrict__ b1,
    const int* __restrict__ tok, const int* __restrict__ cnt, const int* __restrict__ offs,
    const u32* __restrict__ table, const int* __restrict__ meta,
    u16* __restrict__ H1, int p0, int p1,
    const float* __restrict__ W2, u16* __restrict__ W2b)
{
    __shared__ __align__(16) u16 As[BM * BK];   // 16 KiB
    __shared__ __align__(16) u16 Bs[BN * BK];   // 16 KiB
    const int tid = threadIdx.x;                // 0..511
    const int lane = tid & 63, wid = tid >> 6;
    const int wm = wid >> 2, wn = wid & 3;      // 2x4 wave grid; wave C = 64x32

    const int NCOL = HID / BN;                  // 32
    int nt = meta[0];
    int nact = NCOL * nt;
    int bid = blockIdx.x;
    bool active = (bid < nact);
    int e = 0, row0 = 0, ce = 0, oe = 0, col0 = 0;
    if (active) {
        int swz = xcd_swz(bid, nact);
        int tile = swz / NCOL, colb = swz & (NCOL - 1);
        u32 entry = table[tile];
        e = (int)(entry >> 20);
        row0 = (int)(entry & 0xFFFFFu);
        ce = cnt[e]; oe = offs[e];
        col0 = colb * BN;
        active = !(oe + min(ce, row0 + BM) <= p0 || oe + row0 >= p1);
    }

    if (active) {
        f32x4 acc[4][2] = {};
        const u16* Agp = xb;
        const u16* Bgp = W1b;
        size_t aoffA[2], boffB[2];
        {
            CHUNK_RS(0) CHUNK_RS(1)
#define TOKA(rc) ((row0 + (rc)) < ce ? tok[oe + row0 + (rc)] : tok[oe])
            aoffA[0] = (size_t)TOKA(r0) * DMODEL + s0 * 8;
            aoffA[1] = (size_t)TOKA(r1) * DMODEL + s1 * 8;
#undef TOKA
            boffB[0] = ((size_t)e * HID + col0 + r0) * DMODEL + s0 * 8;
            boffB[1] = ((size_t)e * HID + col0 + r1) * DMODEL + s1 * 8;
        }

        M97_LOOP(DMODEL / BK, 0);               // 16 K-steps

        float bias[2];
#pragma unroll
        for (int nf = 0; nf < 2; ++nf)
            bias[nf] = b1[e * HID + col0 + wn * 32 + nf * 16 + (lane & 15)];

#pragma unroll
        for (int mf = 0; mf < 4; ++mf) {
#pragma unroll
            for (int j = 0; j < 4; ++j) {
                int r = wm * 64 + mf * 16 + ((lane >> 4) * 4) + j;
                int gi = row0 + r;
                int p = oe + gi;
                if (gi < ce && p >= p0 && p < p1) {
                    u16* hrow = H1 + (size_t)(p - p0) * HID;
#pragma unroll
                    for (int nf = 0; nf < 2; ++nf) {
                        int n = col0 + wn * 32 + nf * 16 + (lane & 15);
                        hrow[n] = f2b(gelu_fast(acc[mf][nf][j] + bias[nf]));
                    }
                }
            }
        }
    }

    // folded W2 convert (pass 0 only); kernel boundary orders it before gemm2
    if (p0 == 0) {
        long n8 = (long)NEXP * DMODEL * HID / 8;
        long stride = (long)gridDim.x * 512;
        for (long i = (long)bid * 512 + tid; i < n8; i += stride) {
            const float4* p = (const float4*)(W2 + i * 8);
            float4 f0 = p[0], f1 = p[1];
            *(s16x8*)(W2b + i * 8) = cvt8(f0, f1);
        }
    }
}

// GEMM2 (K-split x2 into two Opair planes, no atomics):
// Opair[kh][p, d] = wgt[p]*(sum_{h in half} H1[p,h]*W2b[e,d,h]) + (kh==0)*b2
__global__ __launch_bounds__(512, 4) void gemm2_kernel(
    const u16* __restrict__ H1, const u16* __restrict__ W2b, const float* __restrict__ b2,
    const float* __restrict__ wgt,
    const int* __restrict__ cnt, const int* __restrict__ offs,
    const u32* __restrict__ table, const int* __restrict__ meta,
    u16* __restrict__ Opair, int p0, int p1)
{
    __shared__ __align__(16) u16 As[BM * BK];
    __shared__ __align__(16) u16 Bs[BN * BK];
    const int tid = threadIdx.x;
    const int lane = tid & 63, wid = tid >> 6;
    const int wm = wid >> 2, wn = wid & 3;

    int nt = meta[0];
    int nact = 16 * nt;                         // 8 colb x 2 khalf
    int bid = blockIdx.x;
    if (bid >= nact) return;
    int swz = xcd_swz(bid, nact);
    int tile = swz >> 4;
    int rem = swz & 15;
    int colb = rem >> 1, khalf = rem & 1;
    u32 entry = table[tile];
    const int e = (int)(entry >> 20);
    const int row0 = (int)(entry & 0xFFFFFu);
    const int ce = cnt[e], oe = offs[e];
    if (oe + min(ce, row0 + BM) <= p0 || oe + row0 >= p1) return;
    const int col0 = colb * BN;
    const int kbase = khalf * (HID / 2);

    f32x4 acc[4][2] = {};

    const u16* Agp = H1;
    const u16* Bgp = W2b;
    const int smax = p1 - p0 - 1;
    size_t aoffA[2], boffB[2];
    {
        CHUNK_RS(0) CHUNK_RS(1)
#define AIDX(rc) ({ int ai_ = oe + row0 + (rc) - p0;                         \
                    ai_ < 0 ? 0 : (ai_ > smax ? smax : ai_); })
        aoffA[0] = (size_t)AIDX(r0) * HID + s0 * 8 + kbase;
        aoffA[1] = (size_t)AIDX(r1) * HID + s1 * 8 + kbase;
#undef AIDX
        boffB[0] = ((size_t)e * DMODEL + col0 + r0) * HID + s0 * 8 + kbase;
        boffB[1] = ((size_t)e * DMODEL + col0 + r1) * HID + s1 * 8 + kbase;
    }

    M97_LOOP(HID / 2 / BK, 0);                  // 32 K-steps of this khalf

    float bias[2];
#pragma unroll
    for (int nf = 0; nf < 2; ++nf)
        bias[nf] = (khalf == 0)
            ? b2[e * DMODEL + col0 + wn * 32 + nf * 16 + (lane & 15)] : 0.0f;

    u16* Opl = Opair + (size_t)khalf * NPAIR * DMODEL;
#pragma unroll
    for (int mf = 0; mf < 4; ++mf) {
#pragma unroll
        for (int j = 0; j < 4; ++j) {
            int r = wm * 64 + mf * 16 + ((lane >> 4) * 4) + j;
            int gi = row0 + r;
            int p = oe + gi;
            if (gi < ce && p >= p0 && p < p1) {
                float w = wgt[p];
                u16* orow = Opl + (size_t)p * DMODEL;
#pragma unroll
                for (int nf = 0; nf < 2; ++nf) {
                    int n = col0 + wn * 32 + nf * 16 + (lane & 15);
                    orow[n] = f2b(w * (acc[mf][nf][j] + bias[nf]));
                }
            }
        }
    }
}

// ---------------- host launcher ----------------
extern "C" void kernel_launch(void* const* d_in, const int* in_sizes, int n_in,
                              void* d_out, int out_size, void* d_ws, size_t ws_size,
                              hipStream_t stream)
{
    const float* x  = (const float*)d_in[0];
    const float* Wr = (const float*)d_in[1];
    const float* br = (const float*)d_in[2];
    const float* W1 = (const float*)d_in[3];
    const float* b1 = (const float*)d_in[4];
    const float* W2 = (const float*)d_in[5];
    const float* b2 = (const float*)d_in[6];
    float* out = (float*)d_out;

    char* ws = (char*)d_ws;
    u16* xb = (u16*)ws;                               // 16 MiB
    size_t o2 = (size_t)T_TOK * DMODEL * 2;
    int*   cnt   = (int*)(ws + o2);                   // 8 ints
    int*   offs  = (int*)(ws + o2 + 64);              // 9 ints
    int*   meta  = (int*)(ws + o2 + 192);
    u32*   table = (u32*)(ws + o2 + 256);             // <=136 entries
    int*   fill  = (int*)(ws + o2 + 1024);            // padded: 8 x 128B
    int*   topi  = (int*)(ws + o2 + 4096);
    float* topw  = (float*)(ws + o2 + 4096 + (size_t)NPAIR * 4);
    int*   tok   = (int*)(ws + o2 + 4096 + (size_t)NPAIR * 8);
    float* wgt   = (float*)(ws + o2 + 4096 + (size_t)NPAIR * 12);
    int*   pos   = (int*)(ws + o2 + 4096 + (size_t)NPAIR * 16);

    const size_t WBYTES = (size_t)NEXP * DMODEL * HID * 2;   // 64 MiB each
    size_t oW2 = o2 + (2u << 20);
    size_t oW1 = oW2 + WBYTES;
    size_t oOp = oW1 + WBYTES;
    size_t oH  = oOp + (size_t)2 * NPAIR * DMODEL * 2;       // 2 Opair planes, 64 MiB
    u16* W2b   = (u16*)(ws + oW2);
    u16* W1b   = (u16*)(ws + oW1);
    u16* Opair = (u16*)(ws + oOp);
    u16* H1    = (u16*)(ws + oH);

    long long cap = ((long long)ws_size - (long long)oH) / ((long long)HID * 2);
    int slice = cap >= NPAIR ? NPAIR : (cap < 1024 ? 1024 : (int)cap);

    hipMemsetAsync(ws + o2, 0, 2048, stream);          // cnt/offs/meta/fill

    cvt_kernel<<<dim3(1024), 256, 0, stream>>>(x, xb, (long)T_TOK * DMODEL / 8);

    router_kernel<<<dim3(T_TOK / 4), 256, 0, stream>>>(x, Wr, br, topi, topw, W1, W1b);
    count_offsets_kernel<<<dim3(1), 256, 0, stream>>>(topi, cnt, offs, table, meta);
    scatter_kernel<<<dim3(T_TOK / 256), 256, 0, stream>>>(topi, topw, offs, fill, tok, wgt, pos);

    for (int pp = 0; pp < NPAIR; pp += slice) {
        int p1v = pp + slice < NPAIR ? pp + slice : NPAIR;
        gemm1_kernel<<<dim3((HID / BN) * MAXT), 512, 0, stream>>>(
            xb, W1b, b1, tok, cnt, offs, table, meta, H1, pp, p1v, W2, W2b);
        gemm2_kernel<<<dim3(16 * MAXT), 512, 0, stream>>>(
            H1, W2b, b2, wgt, cnt, offs, table, meta, Opair, pp, p1v);
    }

    combine_kernel<<<dim3(T_TOK / 2), 256, 0, stream>>>(Opair, pos, out);
}

// Round 22
// 489.918 us; speedup vs baseline: 1.0154x; 1.0154x over previous
//
#include <hip/hip_runtime.h>

// ---- problem dims (fixed) ----
#define T_TOK 8192      // B*S
#define DMODEL 1024
#define NEXP 8
#define TOPK 2
#define HID 4096
#define NPAIR (T_TOK*TOPK)   // 16384
#define BM 128
#define BN 128
#define BK 64
#define MAXT (NPAIR/128 + NEXP)   // 136 row-tiles upper bound

typedef unsigned short u16;
typedef unsigned int u32;
typedef short s16x8 __attribute__((ext_vector_type(8)));
typedef float f32x4 __attribute__((ext_vector_type(4)));

// fp32 -> bf16 round-to-nearest-even
__device__ __forceinline__ u16 f2b(float f) {
    union { float f; unsigned int u; } v; v.f = f;
    return (u16)((v.u + 0x7fffu + ((v.u >> 16) & 1u)) >> 16);
}
__device__ __forceinline__ float b2f(u16 h) {
    union { unsigned int u; float f; } v; v.u = ((unsigned int)h) << 16;
    return v.f;
}

__device__ __forceinline__ s16x8 cvt8(float4 f0, float4 f1) {
    s16x8 o;
    o[0]=(short)f2b(f0.x); o[1]=(short)f2b(f0.y); o[2]=(short)f2b(f0.z); o[3]=(short)f2b(f0.w);
    o[4]=(short)f2b(f1.x); o[5]=(short)f2b(f1.y); o[6]=(short)f2b(f1.z); o[7]=(short)f2b(f1.w);
    return o;
}

// async global->LDS, 16B per lane; LDS dest linear in lane order
__device__ __forceinline__ void gload16(const void* g, void* l) {
    __builtin_amdgcn_global_load_lds(
        (const __attribute__((address_space(1))) unsigned int*)g,
        (__attribute__((address_space(3))) unsigned int*)l, 16, 0, 0);
}

// tanh-form gelu, exp/rcp in HW
__device__ __forceinline__ float gelu_fast(float v) {
    float y = 0.7978845608028654f * v * fmaf(0.044715f * v, v, 1.0f);
    float t = -2.8853900817779268f * y;   // -2y * log2(e)
    float z, r;
    asm("v_exp_f32 %0, %1" : "=v"(z) : "v"(t));
    float den = 1.0f + z;
    asm("v_rcp_f32 %0, %1" : "=v"(r) : "v"(den));
    return v * r;
}

// m204 bijective XCD swizzle over nact active blocks
__device__ __forceinline__ int xcd_swz(int bid, int nact) {
    int q = nact >> 3, r = nact & 7;
    int xcd = bid & 7, i = bid >> 3;
    return (xcd < r ? xcd * (q + 1) : r * (q + 1) + (xcd - r) * q) + i;
}

// ---------------- fp32 -> bf16 conversion (x only) ----------------
__global__ __launch_bounds__(256) void cvt_kernel(const float* __restrict__ in,
                                                  u16* __restrict__ out, long n8) {
    long stride = (long)gridDim.x * 256;
    for (long i = (long)blockIdx.x * 256 + threadIdx.x; i < n8; i += stride) {
        const float4* p = (const float4*)(in + i * 8);
        float4 f0 = p[0], f1 = p[1];
        *(s16x8*)(out + i * 8) = cvt8(f0, f1);
    }
}

// ---------------- router (NO atomics; topi/topw only + folded W1 convert) ----------------
__global__ __launch_bounds__(256) void router_kernel(
    const float* __restrict__ x, const float* __restrict__ Wr, const float* __restrict__ br,
    int* __restrict__ topi, float* __restrict__ topw,
    const float* __restrict__ W1, u16* __restrict__ W1b)
{
    __shared__ float WrS[NEXP * DMODEL];
    int tid = threadIdx.x;
    const float4* Wr4 = (const float4*)Wr;
    float4* WrS4 = (float4*)WrS;
    for (int i = tid; i < NEXP * DMODEL / 4; i += 256) WrS4[i] = Wr4[i];
    __syncthreads();

    int wid = tid >> 6, lane = tid & 63;
    int t = blockIdx.x * 4 + wid;
    const float* xr = x + (size_t)t * DMODEL;

    float acc[NEXP];
#pragma unroll
    for (int e = 0; e < NEXP; ++e) acc[e] = 0.f;
#pragma unroll 4
    for (int i = lane; i < DMODEL; i += 64) {
        float xv = xr[i];
#pragma unroll
        for (int e = 0; e < NEXP; ++e) acc[e] = fmaf(xv, WrS[e * DMODEL + i], acc[e]);
    }
#pragma unroll
    for (int e = 0; e < NEXP; ++e) {
        float v = acc[e];
#pragma unroll
        for (int off = 32; off > 0; off >>= 1) v += __shfl_xor(v, off);
        acc[e] = v;
    }
    if (lane == 0) {
        float lg[NEXP];
#pragma unroll
        for (int e = 0; e < NEXP; ++e) lg[e] = acc[e] + br[e];
        int i1 = 0;
#pragma unroll
        for (int e = 1; e < NEXP; ++e) if (lg[e] > lg[i1]) i1 = e;
        int i2 = (i1 == 0) ? 1 : 0;
#pragma unroll
        for (int e = 0; e < NEXP; ++e) if (e != i1 && lg[e] > lg[i2]) i2 = e;
        float e2 = expf(lg[i2] - lg[i1]);
        float s = 1.f + e2;
        topi[t * 2] = i1;  topi[t * 2 + 1] = i2;
        topw[t * 2] = 1.f / s;  topw[t * 2 + 1] = e2 / s;
    }

    // folded W1 convert (completes before gemm1 via kernel-boundary ordering)
    long n8 = (long)NEXP * DMODEL * HID / 8;
    long stride = (long)gridDim.x * 256;
    for (long i = (long)blockIdx.x * 256 + tid; i < n8; i += stride) {
        const float4* p = (const float4*)(W1 + i * 8);
        float4 f0 = p[0], f1 = p[1];
        *(s16x8*)(W1b + i * 8) = cvt8(f0, f1);
    }
}

// single-block count + offsets + tile table (no atomics anywhere)
__global__ __launch_bounds__(256) void count_offsets_kernel(
    const int* __restrict__ topi, int* __restrict__ cnt, int* __restrict__ offs,
    u32* __restrict__ table, int* __restrict__ meta)
{
    __shared__ int red[NEXP * 256];
    int tid = threadIdx.x;
    int c[NEXP] = {};
    for (int i = tid; i < NPAIR; i += 256) {
        int e = topi[i];
#pragma unroll
        for (int k = 0; k < NEXP; ++k) c[k] += (e == k) ? 1 : 0;   // static idx (rule #20)
    }
#pragma unroll
    for (int k = 0; k < NEXP; ++k) red[k * 256 + tid] = c[k];
    __syncthreads();
    if (tid < NEXP) {
        int s = 0;
        for (int i = 0; i < 256; ++i) s += red[tid * 256 + i];
        cnt[tid] = s;
    }
    __syncthreads();
    if (tid == 0) {
        int a = 0;
        for (int e = 0; e < NEXP; ++e) { offs[e] = a; a += cnt[e]; }
        offs[NEXP] = a;
        int nt = 0;
        for (int e = 0; e < NEXP; ++e)
            for (int r0 = 0; r0 < cnt[e]; r0 += 128)
                table[nt++] = ((u32)e << 20) | (u32)r0;
        meta[0] = nt;
    }
}

// wave-aggregated scatter; fill padded to 128B/expert (parallel L2 lines)
__global__ __launch_bounds__(256) void scatter_kernel(
    const int* __restrict__ topi, const float* __restrict__ topw,
    const int* __restrict__ offs, int* __restrict__ fill,
    int* __restrict__ tok, float* __restrict__ wgt, int* __restrict__ pos)
{
    int t = blockIdx.x * 256 + threadIdx.x;
    int lane = threadIdx.x & 63;
#pragma unroll
    for (int s = 0; s < TOPK; ++s) {
        int e = topi[t * 2 + s];
        float w = topw[t * 2 + s];
#pragma unroll
        for (int ex = 0; ex < NEXP; ++ex) {
            unsigned long long m = __ballot(e == ex);
            if (e == ex) {
                int ldr = (int)__ffsll((unsigned long long)m) - 1;
                int base = 0;
                if (lane == ldr) base = atomicAdd(&fill[ex * 32], (int)__popcll(m));
                base = __shfl(base, ldr);
                int mypos = base + (int)__popcll(m & ((1ull << lane) - 1ull));
                int p = offs[ex] + mypos;
                tok[p] = t;
                wgt[p] = w;
                pos[t * 2 + s] = p;
            }
        }
    }
}

// combine: out[t][d] = sum over 2 pair-slots x 2 K-half planes of Opair
__global__ __launch_bounds__(256) void combine_kernel(
    const u16* __restrict__ Op, const int* __restrict__ pos, float* __restrict__ out)
{
    const size_t PL = (size_t)NPAIR * DMODEL;   // plane stride
    int tid = threadIdx.x;
    int t = blockIdx.x * 2 + (tid >> 7);
    int c = (tid & 127) * 8;
    int pa = pos[t * 2], pb = pos[t * 2 + 1];
    s16x8 a0 = *(const s16x8*)(Op + (size_t)pa * DMODEL + c);
    s16x8 a1 = *(const s16x8*)(Op + PL + (size_t)pa * DMODEL + c);
    s16x8 b0 = *(const s16x8*)(Op + (size_t)pb * DMODEL + c);
    s16x8 b1 = *(const s16x8*)(Op + PL + (size_t)pb * DMODEL + c);
    float* o = out + (size_t)t * DMODEL + c;
    float4 o0, o1;
    o0.x = (b2f((u16)a0[0]) + b2f((u16)a1[0])) + (b2f((u16)b0[0]) + b2f((u16)b1[0]));
    o0.y = (b2f((u16)a0[1]) + b2f((u16)a1[1])) + (b2f((u16)b0[1]) + b2f((u16)b1[1]));
    o0.z = (b2f((u16)a0[2]) + b2f((u16)a1[2])) + (b2f((u16)b0[2]) + b2f((u16)b1[2]));
    o0.w = (b2f((u16)a0[3]) + b2f((u16)a1[3])) + (b2f((u16)b0[3]) + b2f((u16)b1[3]));
    o1.x = (b2f((u16)a0[4]) + b2f((u16)a1[4])) + (b2f((u16)b0[4]) + b2f((u16)b1[4]));
    o1.y = (b2f((u16)a0[5]) + b2f((u16)a1[5])) + (b2f((u16)b0[5]) + b2f((u16)b1[5]));
    o1.z = (b2f((u16)a0[6]) + b2f((u16)a1[6])) + (b2f((u16)b0[6]) + b2f((u16)b1[6]));
    o1.w = (b2f((u16)a0[7]) + b2f((u16)a1[7])) + (b2f((u16)b0[7]) + b2f((u16)b1[7]));
    ((float4*)o)[0] = o0;
    ((float4*)o)[1] = o1;
}

// ======== m97-replica GEMM core: 128x128, BK=64, 256 thr (2x2 waves), ========
// SINGLE 32 KiB LDS buffer, 2 barriers per 64-K step, cross-block overlap.
// Rows are 128 B = 8 slots of 16 B; slot = s ^ (row&7) (verified R2-R4).
#define STAGE_TILE(koff) do {                                               \
    _Pragma("unroll") for (int c = 0; c < 4; ++c) {                         \
        int idx = c * 256 + tid;                                            \
        gload16(Agp + aoffA[c] + (size_t)(koff), (char*)As + idx * 16);     \
        gload16(Bgp + boffB[c] + (size_t)(koff), (char*)Bs + idx * 16);     \
    }                                                                       \
} while (0)

#define COMPUTE_TILE() do {                                                 \
    _Pragma("unroll") for (int half = 0; half < 2; ++half) {                \
        s16x8 av[4], bv[4];                                                 \
        int kslot = half * 4 + (lane >> 4);                                 \
        _Pragma("unroll") for (int mi = 0; mi < 4; ++mi) {                  \
            int rr = wm * 64 + mi * 16 + (lane & 15);                       \
            av[mi] = *(const s16x8*)((char*)As + rr * 128 + ((kslot ^ (rr & 7)) * 16)); } \
        _Pragma("unroll") for (int nf = 0; nf < 4; ++nf) {                  \
            int rb = wn * 64 + nf * 16 + (lane & 15);                       \
            bv[nf] = *(const s16x8*)((char*)Bs + rb * 128 + ((kslot ^ (rb & 7)) * 16)); } \
        _Pragma("unroll") for (int mi = 0; mi < 4; ++mi)                    \
        _Pragma("unroll") for (int nf = 0; nf < 4; ++nf)                    \
            acc[mi][nf] = __builtin_amdgcn_mfma_f32_16x16x32_bf16(          \
                av[mi], bv[nf], acc[mi][nf], 0, 0, 0);                      \
    }                                                                       \
} while (0)

#define VM0() asm volatile("s_waitcnt vmcnt(0)" ::: "memory")

#define M97_LOOP(NT, KBASE) do {                                            \
    _Pragma("unroll 1")                                                     \
    for (int t = 0; t < (NT); ++t) {                                        \
        STAGE_TILE((size_t)(KBASE) + (size_t)t * BK);                       \
        VM0();                                                              \
        __syncthreads();                                                    \
        COMPUTE_TILE();                                                     \
        __syncthreads();                                                    \
    }                                                                       \
} while (0)

// staging chunk math: 1024 chunks/operand (128 rows x 8 slots), 4/thread
#define CHUNK_RS(c)                                                         \
    int r##c = ((c) * 256 + tid) >> 3;                                      \
    int s##c = (tid & 7) ^ (r##c & 7);

// GEMM1: H1[p, n] = gelu( sum_d xb[tok[p], d] * W1b[e, n, d] + b1[e, n] )
// + folded W2 fp32->bf16 convert on pass 0
__global__ __launch_bounds__(256, 3) void gemm1_kernel(
    const u16* __restrict__ xb, const u16* __restrict__ W1b, const float* __restrict__ b1,
    const int* __restrict__ tok, const int* __restrict__ cnt, const int* __restrict__ offs,
    const u32* __restrict__ table, const int* __restrict__ meta,
    u16* __restrict__ H1, int p0, int p1,
    const float* __restrict__ W2, u16* __restrict__ W2b)
{
    __shared__ __align__(16) u16 As[BM * BK];   // 16 KiB
    __shared__ __align__(16) u16 Bs[BN * BK];   // 16 KiB
    const int tid = threadIdx.x;                // 0..255
    const int lane = tid & 63, wid = tid >> 6;
    const int wm = wid >> 1, wn = wid & 1;      // 2x2 wave grid; wave C = 64x64

    const int NCOL = HID / BN;                  // 32
    int nt = meta[0];
    int nact = NCOL * nt;
    int bid = blockIdx.x;
    bool active = (bid < nact);
    int e = 0, row0 = 0, ce = 0, oe = 0, col0 = 0;
    if (active) {
        int swz = xcd_swz(bid, nact);
        int tile = swz / NCOL, colb = swz & (NCOL - 1);
        u32 entry = table[tile];
        e = (int)(entry >> 20);
        row0 = (int)(entry & 0xFFFFFu);
        ce = cnt[e]; oe = offs[e];
        col0 = colb * BN;
        active = !(oe + min(ce, row0 + BM) <= p0 || oe + row0 >= p1);
    }

    if (active) {
        f32x4 acc[4][4] = {};
        const u16* Agp = xb;
        const u16* Bgp = W1b;
        size_t aoffA[4], boffB[4];
        {
            CHUNK_RS(0) CHUNK_RS(1) CHUNK_RS(2) CHUNK_RS(3)
#define TOKA(rc) ((row0 + (rc)) < ce ? tok[oe + row0 + (rc)] : tok[oe])
            aoffA[0] = (size_t)TOKA(r0) * DMODEL + s0 * 8;
            aoffA[1] = (size_t)TOKA(r1) * DMODEL + s1 * 8;
            aoffA[2] = (size_t)TOKA(r2) * DMODEL + s2 * 8;
            aoffA[3] = (size_t)TOKA(r3) * DMODEL + s3 * 8;
#undef TOKA
            boffB[0] = ((size_t)e * HID + col0 + r0) * DMODEL + s0 * 8;
            boffB[1] = ((size_t)e * HID + col0 + r1) * DMODEL + s1 * 8;
            boffB[2] = ((size_t)e * HID + col0 + r2) * DMODEL + s2 * 8;
            boffB[3] = ((size_t)e * HID + col0 + r3) * DMODEL + s3 * 8;
        }

        M97_LOOP(DMODEL / BK, 0);               // 16 K-steps

        float bias[4];
#pragma unroll
        for (int nf = 0; nf < 4; ++nf)
            bias[nf] = b1[e * HID + col0 + wn * 64 + nf * 16 + (lane & 15)];

#pragma unroll
        for (int mf = 0; mf < 4; ++mf) {
#pragma unroll
            for (int j = 0; j < 4; ++j) {
                int r = wm * 64 + mf * 16 + ((lane >> 4) * 4) + j;
                int gi = row0 + r;
                int p = oe + gi;
                if (gi < ce && p >= p0 && p < p1) {
                    u16* hrow = H1 + (size_t)(p - p0) * HID;
#pragma unroll
                    for (int nf = 0; nf < 4; ++nf) {
                        int n = col0 + wn * 64 + nf * 16 + (lane & 15);
                        hrow[n] = f2b(gelu_fast(acc[mf][nf][j] + bias[nf]));
                    }
                }
            }
        }
    }

    // folded W2 convert (pass 0 only); kernel boundary orders it before gemm2
    if (p0 == 0) {
        long n8 = (long)NEXP * DMODEL * HID / 8;
        long stride = (long)gridDim.x * 256;
        for (long i = (long)bid * 256 + tid; i < n8; i += stride) {
            const float4* p = (const float4*)(W2 + i * 8);
            float4 f0 = p[0], f1 = p[1];
            *(s16x8*)(W2b + i * 8) = cvt8(f0, f1);
        }
    }
}

// GEMM2 (K-split x2 into two Opair planes, no atomics):
// Opair[kh][p, d] = wgt[p]*(sum_{h in half} H1[p,h]*W2b[e,d,h]) + (kh==0)*b2
__global__ __launch_bounds__(256, 3) void gemm2_kernel(
    const u16* __restrict__ H1, const u16* __restrict__ W2b, const float* __restrict__ b2,
    const float* __restrict__ wgt,
    const int* __restrict__ cnt, const int* __restrict__ offs,
    const u32* __restrict__ table, const int* __restrict__ meta,
    u16* __restrict__ Opair, int p0, int p1)
{
    __shared__ __align__(16) u16 As[BM * BK];
    __shared__ __align__(16) u16 Bs[BN * BK];
    const int tid = threadIdx.x;
    const int lane = tid & 63, wid = tid >> 6;
    const int wm = wid >> 1, wn = wid & 1;

    int nt = meta[0];
    int nact = 16 * nt;                         // 8 colb x 2 khalf
    int bid = blockIdx.x;
    if (bid >= nact) return;
    int swz = xcd_swz(bid, nact);
    int tile = swz >> 4;
    int rem = swz & 15;
    int colb = rem >> 1, khalf = rem & 1;
    u32 entry = table[tile];
    const int e = (int)(entry >> 20);
    const int row0 = (int)(entry & 0xFFFFFu);
    const int ce = cnt[e], oe = offs[e];
    if (oe + min(ce, row0 + BM) <= p0 || oe + row0 >= p1) return;
    const int col0 = colb * BN;
    const int kbase = khalf * (HID / 2);

    f32x4 acc[4][4] = {};

    const u16* Agp = H1;
    const u16* Bgp = W2b;
    const int smax = p1 - p0 - 1;
    size_t aoffA[4], boffB[4];
    {
        CHUNK_RS(0) CHUNK_RS(1) CHUNK_RS(2) CHUNK_RS(3)
#define AIDX(rc) ({ int ai_ = oe + row0 + (rc) - p0;                         \
                    ai_ < 0 ? 0 : (ai_ > smax ? smax : ai_); })
        aoffA[0] = (size_t)AIDX(r0) * HID + s0 * 8 + kbase;
        aoffA[1] = (size_t)AIDX(r1) * HID + s1 * 8 + kbase;
        aoffA[2] = (size_t)AIDX(r2) * HID + s2 * 8 + kbase;
        aoffA[3] = (size_t)AIDX(r3) * HID + s3 * 8 + kbase;
#undef AIDX
        boffB[0] = ((size_t)e * DMODEL + col0 + r0) * HID + s0 * 8 + kbase;
        boffB[1] = ((size_t)e * DMODEL + col0 + r1) * HID + s1 * 8 + kbase;
        boffB[2] = ((size_t)e * DMODEL + col0 + r2) * HID + s2 * 8 + kbase;
        boffB[3] = ((size_t)e * DMODEL + col0 + r3) * HID + s3 * 8 + kbase;
    }

    M97_LOOP(HID / 2 / BK, 0);                  // 32 K-steps of this khalf

    float bias[4];
#pragma unroll
    for (int nf = 0; nf < 4; ++nf)
        bias[nf] = (khalf == 0)
            ? b2[e * DMODEL + col0 + wn * 64 + nf * 16 + (lane & 15)] : 0.0f;

    u16* Opl = Opair + (size_t)khalf * NPAIR * DMODEL;
#pragma unroll
    for (int mf = 0; mf < 4; ++mf) {
#pragma unroll
        for (int j = 0; j < 4; ++j) {
            int r = wm * 64 + mf * 16 + ((lane >> 4) * 4) + j;
            int gi = row0 + r;
            int p = oe + gi;
            if (gi < ce && p >= p0 && p < p1) {
                float w = wgt[p];
                u16* orow = Opl + (size_t)p * DMODEL;
#pragma unroll
                for (int nf = 0; nf < 4; ++nf) {
                    int n = col0 + wn * 64 + nf * 16 + (lane & 15);
                    orow[n] = f2b(w * (acc[mf][nf][j] + bias[nf]));
                }
            }
        }
    }
}

// ---------------- host launcher ----------------
extern "C" void kernel_launch(void* const* d_in, const int* in_sizes, int n_in,
                              void* d_out, int out_size, void* d_ws, size_t ws_size,
                              hipStream_t stream)
{
    const float* x  = (const float*)d_in[0];
    const float* Wr = (const float*)d_in[1];
    const float* br = (const float*)d_in[2];
    const float* W1 = (const float*)d_in[3];
    const float* b1 = (const float*)d_in[4];
    const float* W2 = (const float*)d_in[5];
    const float* b2 = (const float*)d_in[6];
    float* out = (float*)d_out;

    char* ws = (char*)d_ws;
    u16* xb = (u16*)ws;                               // 16 MiB
    size_t o2 = (size_t)T_TOK * DMODEL * 2;
    int*   cnt   = (int*)(ws + o2);                   // 8 ints
    int*   offs  = (int*)(ws + o2 + 64);              // 9 ints
    int*   meta  = (int*)(ws + o2 + 192);
    u32*   table = (u32*)(ws + o2 + 256);             // <=136 entries
    int*   fill  = (int*)(ws + o2 + 1024);            // padded: 8 x 128B
    int*   topi  = (int*)(ws + o2 + 4096);
    float* topw  = (float*)(ws + o2 + 4096 + (size_t)NPAIR * 4);
    int*   tok   = (int*)(ws + o2 + 4096 + (size_t)NPAIR * 8);
    float* wgt   = (float*)(ws + o2 + 4096 + (size_t)NPAIR * 12);
    int*   pos   = (int*)(ws + o2 + 4096 + (size_t)NPAIR * 16);

    const size_t WBYTES = (size_t)NEXP * DMODEL * HID * 2;   // 64 MiB each
    size_t oW2 = o2 + (2u << 20);
    size_t oW1 = oW2 + WBYTES;
    size_t oOp = oW1 + WBYTES;
    size_t oH  = oOp + (size_t)2 * NPAIR * DMODEL * 2;       // 2 Opair planes, 64 MiB
    u16* W2b   = (u16*)(ws + oW2);
    u16* W1b   = (u16*)(ws + oW1);
    u16* Opair = (u16*)(ws + oOp);
    u16* H1    = (u16*)(ws + oH);

    long long cap = ((long long)ws_size - (long long)oH) / ((long long)HID * 2);
    int slice = cap >= NPAIR ? NPAIR : (cap < 1024 ? 1024 : (int)cap);

    hipMemsetAsync(ws + o2, 0, 2048, stream);          // cnt/offs/meta/fill

    cvt_kernel<<<dim3(1024), 256, 0, stream>>>(x, xb, (long)T_TOK * DMODEL / 8);

    router_kernel<<<dim3(T_TOK / 4), 256, 0, stream>>>(x, Wr, br, topi, topw, W1, W1b);
    count_offsets_kernel<<<dim3(1), 256, 0, stream>>>(topi, cnt, offs, table, meta);
    scatter_kernel<<<dim3(T_TOK / 256), 256, 0, stream>>>(topi, topw, offs, fill, tok, wgt, pos);

    for (int pp = 0; pp < NPAIR; pp += slice) {
        int p1v = pp + slice < NPAIR ? pp + slice : NPAIR;
        gemm1_kernel<<<dim3((HID / BN) * MAXT), 256, 0, stream>>>(
            xb, W1b, b1, tok, cnt, offs, table, meta, H1, pp, p1v, W2, W2b);
        gemm2_kernel<<<dim3(16 * MAXT), 256, 0, stream>>>(
            H1, W2b, b2, wgt, cnt, offs, table, meta, Opair, pp, p1v);
    }

    combine_kernel<<<dim3(T_TOK / 2), 256, 0, stream>>>(Opair, pos, out);
}